// Round 1
// baseline (145.685 us; speedup 1.0000x reference)
//
#include <hip/hip_runtime.h>
#include <math.h>

#define NEL   4096
#define NT    1024
#define NWAVES (NT / 64)

// ---------------------------------------------------------------------------
// block-wide double reduction (16 waves)
// ---------------------------------------------------------------------------
__device__ inline double block_reduce(double v, double* smem) {
  const int lane = threadIdx.x & 63;
  const int wid  = threadIdx.x >> 6;
#pragma unroll
  for (int d = 32; d > 0; d >>= 1) v += __shfl_down(v, d, 64);
  if (lane == 0) smem[wid] = v;
  __syncthreads();
  double r;
  if (wid == 0) {
    r = (lane < NWAVES) ? smem[lane] : 0.0;
#pragma unroll
    for (int d = 8; d > 0; d >>= 1) r += __shfl_down(r, d, 64);
    if (lane == 0) smem[0] = r;
  }
  __syncthreads();
  r = smem[0];
  __syncthreads();
  return r;
}

// ---------------------------------------------------------------------------
// Kernel 1: per array (blockIdx.x = 0:pred, 1:target)
//   sort desc -> prefix sums of z = s - w (double) -> D&C PAV -> ranks,
//   scattered to ws by original index.
// ---------------------------------------------------------------------------
__global__ __launch_bounds__(NT)
void rank_kernel(const float* __restrict__ pred,
                 const float* __restrict__ target,
                 float* __restrict__ ranks) {
  __shared__ float  s_val[NEL];
  __shared__ int    s_idx[NEL];
  __shared__ double s_P[NEL + 1];
  __shared__ int    s_cnt[NEL];      // block lengths; reused as bstart[] later
  __shared__ double s_wsum[NWAVES];
  __shared__ int    s_nb;

  const int tid = threadIdx.x;
  const float* __restrict__ x = (blockIdx.x == 0) ? pred : target;
  float* __restrict__ out = ranks + blockIdx.x * NEL;

  // load (REG_STRENGTH = 1.0 -> theta = x)
  for (int i = tid; i < NEL; i += NT) { s_val[i] = x[i]; s_idx[i] = i; }
  __syncthreads();

  // ---- bitonic sort, descending by value, tiebreak ascending index -------
  for (int k = 2; k <= NEL; k <<= 1) {
    for (int j = k >> 1; j > 0; j >>= 1) {
      for (int t = tid; t < NEL; t += NT) {
        const int l = t ^ j;
        if (l > t) {
          float va = s_val[t], vb = s_val[l];
          int   ia = s_idx[t], ib = s_idx[l];
          // "a first" under (value desc, index asc) total order
          bool aFirst = (va > vb) || (va == vb && ia < ib);
          bool desc   = ((t & k) == 0);
          if (desc ? !aFirst : aFirst) {
            s_val[t] = vb; s_val[l] = va;
            s_idx[t] = ib; s_idx[l] = ia;
          }
        }
      }
      __syncthreads();
    }
  }

  // ---- double prefix sums of z_i = s_i - (NEL - i) ------------------------
  const int base = tid * 4;
  double a0 = (double)s_val[base + 0] - (double)(NEL - (base + 0));
  double a1 = (double)s_val[base + 1] - (double)(NEL - (base + 1));
  double a2 = (double)s_val[base + 2] - (double)(NEL - (base + 2));
  double a3 = (double)s_val[base + 3] - (double)(NEL - (base + 3));
  double c0 = a0, c1 = c0 + a1, c2 = c1 + a2, c3 = c2 + a3;
  const double tsum = c3;

  const int lane = tid & 63, wid = tid >> 6;
  double sc = tsum;
#pragma unroll
  for (int d = 1; d < 64; d <<= 1) {
    double o = __shfl_up(sc, d, 64);
    if (lane >= d) sc += o;
  }
  if (lane == 63) s_wsum[wid] = sc;
  __syncthreads();
  if (tid == 0) {
    double acc = 0.0;
    for (int w = 0; w < NWAVES; w++) { double t = s_wsum[w]; s_wsum[w] = acc; acc += t; }
  }
  __syncthreads();
  const double excl = s_wsum[wid] + (sc - tsum);  // exclusive prefix before base
  s_P[base + 1] = excl + c0;
  s_P[base + 2] = excl + c1;
  s_P[base + 3] = excl + c2;
  s_P[base + 4] = excl + c3;
  if (tid == 0) s_P[0] = 0.0;

  for (int i = tid; i < NEL; i += NT) s_cnt[i] = 1;
  __syncthreads();

  // ---- divide & conquer PAV (non-increasing isotonic) ---------------------
  // invariant: for each block [a,b]: s_cnt[a] == s_cnt[b] == b-a+1
  for (int m = 1; m < NEL; m <<= 1) {
    const int nmerge = NEL / (2 * m);
    for (int t = tid; t < nmerge; t += NT) {
      const int lo = t * 2 * m, mid = lo + m, hi = lo + 2 * m;
      int llen = s_cnt[mid - 1];
      int cs = mid - llen;                 // pooled-candidate start
      int rlen = s_cnt[mid];
      int ce = mid + rlen - 1;             // pooled-candidate end
      double mL = (s_P[mid] - s_P[cs]) / (double)llen;
      double mR = (s_P[ce + 1] - s_P[mid]) / (double)rlen;
      if (mL <= mR) {                      // boundary violation -> pool
        double mu = (s_P[ce + 1] - s_P[cs]) / (double)(ce - cs + 1);
        bool changed = true;
        while (changed) {
          changed = false;
          while (cs > lo) {                // absorb left blocks with mean <= mu
            int l2 = s_cnt[cs - 1];
            double m2 = (s_P[cs] - s_P[cs - l2]) / (double)l2;
            if (m2 <= mu) {
              cs -= l2;
              mu = (s_P[ce + 1] - s_P[cs]) / (double)(ce - cs + 1);
              changed = true;
            } else break;
          }
          while (ce < hi - 1) {            // absorb right blocks with mean >= mu
            int l2 = s_cnt[ce + 1];
            double m2 = (s_P[ce + 1 + l2] - s_P[ce + 1]) / (double)l2;
            if (m2 >= mu) {
              ce += l2;
              mu = (s_P[ce + 1] - s_P[cs]) / (double)(ce - cs + 1);
              changed = true;
            } else break;
          }
        }
        const int len = ce - cs + 1;
        s_cnt[cs] = len;
        s_cnt[ce] = len;
      }
    }
    __syncthreads();
  }

  // ---- walk block list (reuse s_cnt as bstart; read-before-write safe:
  //      write index b <= read index s always, read happens first) ----------
  if (tid == 0) {
    int s = 0, b = 0;
    while (s < NEL) {
      int c = s_cnt[s];   // read BEFORE the aliased write below
      s_cnt[b] = s;
      b++;
      s += c;
    }
    s_nb = b;
  }
  __syncthreads();
  const int nb = s_nb;

  // ---- per element: find block (binary search), rank = s_i - blockmean ----
  for (int e = 0; e < 4; e++) {
    const int i = base + e;
    int loB = 0, hiB = nb - 1;
    while (loB < hiB) {
      int md = (loB + hiB + 1) >> 1;
      if (s_cnt[md] <= i) loB = md; else hiB = md - 1;
    }
    const int st = s_cnt[loB];
    const int en = (loB + 1 < nb) ? s_cnt[loB + 1] : NEL;
    const double v = (s_P[en] - s_P[st]) / (double)(en - st);
    const float r = (float)((double)s_val[i] - v);
    out[s_idx[i]] = r;   // scatter back to original order
  }
}

// ---------------------------------------------------------------------------
// Kernel 2: loss = 1 - Pearson corr of the two rank vectors (two-pass, double)
// ---------------------------------------------------------------------------
__global__ __launch_bounds__(NT)
void loss_kernel(const float* __restrict__ ranks, float* __restrict__ loss_out) {
  __shared__ double s_red[NWAVES];
  const int tid = threadIdx.x;

  float p[4], q[4];
#pragma unroll
  for (int e = 0; e < 4; e++) {
    const int i = tid + e * NT;
    p[e] = ranks[i];
    q[e] = ranks[NEL + i];
  }
  double sp = 0.0, sq = 0.0;
#pragma unroll
  for (int e = 0; e < 4; e++) { sp += (double)p[e]; sq += (double)q[e]; }
  sp = block_reduce(sp, s_red);
  sq = block_reduce(sq, s_red);
  const double mp = sp / (double)NEL;
  const double mq = sq / (double)NEL;

  double va = 0.0, vb = 0.0, vc = 0.0;
#pragma unroll
  for (int e = 0; e < 4; e++) {
    const double dp = (double)p[e] - mp;
    const double dq = (double)q[e] - mq;
    va += dp * dp;
    vb += dq * dq;
    vc += dp * dq;
  }
  va = block_reduce(va, s_red);
  vb = block_reduce(vb, s_red);
  vc = block_reduce(vc, s_red);

  if (tid == 0) loss_out[0] = (float)(1.0 - vc / sqrt(va * vb));
}

// ---------------------------------------------------------------------------
extern "C" void kernel_launch(void* const* d_in, const int* in_sizes, int n_in,
                              void* d_out, int out_size, void* d_ws, size_t ws_size,
                              hipStream_t stream) {
  const float* pred   = (const float*)d_in[0];
  const float* target = (const float*)d_in[1];
  float* ranks = (float*)d_ws;          // 2 * NEL floats
  float* out   = (float*)d_out;

  hipLaunchKernelGGL(rank_kernel, dim3(2), dim3(NT), 0, stream, pred, target, ranks);
  hipLaunchKernelGGL(loss_kernel, dim3(1), dim3(NT), 0, stream, ranks, out);
}

// Round 2
// 87.564 us; speedup vs baseline: 1.6638x; 1.6638x over previous
//
#include <hip/hip_runtime.h>
#include <math.h>

#define NEL   4096
#define NT    1024
#define HALF  512           // threads per array in the fused kernel
#define EPT   (NEL / HALF)  // 8 elements per thread per array
#define CB    256           // count_kernel block size / tile

// ---------------------------------------------------------------------------
// Kernel A: exact stable descending ranks by brute-force counting.
// grid = (NEL/CB, NEL/CB, 2). r_i = #{ j : x_j > x_i  or (x_j==x_i and j<i) }.
// Barrier-free (1 barrier), embarrassingly parallel -> fills all CUs.
// counts must be zeroed before launch (hipMemsetAsync in kernel_launch).
// ---------------------------------------------------------------------------
__global__ __launch_bounds__(CB)
void count_kernel(const float* __restrict__ pred,
                  const float* __restrict__ target,
                  int* __restrict__ counts) {
  __shared__ float jv[CB];
  const int arr = blockIdx.z;
  const float* __restrict__ x = arr ? target : pred;
  const int i     = blockIdx.x * CB + threadIdx.x;
  const int jbase = blockIdx.y * CB;

  jv[threadIdx.x] = x[jbase + threadIdx.x];
  const float xi = x[i];
  __syncthreads();

  int c = 0;
#pragma unroll 8
  for (int t = 0; t < CB; t++) {
    const float v = jv[t];               // wave-uniform LDS broadcast (free)
    const int   j = jbase + t;
    c += (v > xi || (v == xi && j < i)) ? 1 : 0;
  }
  atomicAdd(&counts[arr * NEL + i], c);  // 16 adds per address, low contention
}

// ---------------------------------------------------------------------------
// Kernel B (one block, 1024 threads): both arrays processed in parallel halves
// with aligned barrier structure.
//   scatter sorted -> double prefix sums of z = s - (NEL-pos) -> D&C PAV
//   -> ranks -> Pearson correlation -> loss scalar.
// LDS: 2*(16K + 32.8K + 16K) + eps ~= 130 KB (fits 160 KB/CU).
// ---------------------------------------------------------------------------
__global__ __launch_bounds__(NT)
void pav_loss_kernel(const float* __restrict__ pred,
                     const float* __restrict__ target,
                     const int* __restrict__ counts,
                     float* __restrict__ loss_out) {
  __shared__ float  s_val[2][NEL];
  __shared__ double s_P[2][NEL + 1];
  __shared__ int    s_cnt[2][NEL];     // block-length stamps; later bstart[];
                                       // later float rank_sorted[]
  __shared__ double s_wsum[2][HALF / 64];
  __shared__ int    s_nb[2];
  __shared__ double s_red[NT / 64][5];

  const int tid  = threadIdx.x;
  const int arr  = tid >> 9;           // 0: pred, 1: target
  const int tA   = tid & (HALF - 1);   // thread id within half
  const int lane = tid & 63;
  const int wA   = tA >> 6;            // wave within half, 0..7
  const float* __restrict__ x = arr ? target : pred;
  const int* __restrict__ cnt = counts + arr * NEL;
  const int base = tA * EPT;           // this thread's 8 indices (orig AND sorted)

  // ---- load + scatter into descending-sorted order ------------------------
  int   r[EPT];
  float xv[EPT];
#pragma unroll
  for (int e = 0; e < EPT; e++) {
    const int i = base + e;
    xv[e] = x[i];
    r[e]  = cnt[i];
    s_val[arr][r[e]] = xv[e];          // sorted[r] = x[i]
  }
  __syncthreads();

  // ---- double prefix sums of z_p = s_p - (NEL - p) ------------------------
  double c[EPT];
  double acc = 0.0;
#pragma unroll
  for (int e = 0; e < EPT; e++) {
    const int p = base + e;
    acc += (double)s_val[arr][p] - (double)(NEL - p);
    c[e] = acc;
  }
  double sc = acc;                     // wave-inclusive scan of per-thread sums
#pragma unroll
  for (int d = 1; d < 64; d <<= 1) {
    const double o = __shfl_up(sc, d, 64);
    if (lane >= d) sc += o;
  }
  if (lane == 63) s_wsum[arr][wA] = sc;
  __syncthreads();
  if (tA == 0) {                       // serial exclusive scan over 8 waves
    double a2 = 0.0;
    for (int w = 0; w < HALF / 64; w++) {
      const double t = s_wsum[arr][w];
      s_wsum[arr][w] = a2;
      a2 += t;
    }
  }
  __syncthreads();
  const double excl = s_wsum[arr][wA] + (sc - acc);
#pragma unroll
  for (int e = 0; e < EPT; e++) s_P[arr][base + e + 1] = excl + c[e];
  if (tA == 0) s_P[arr][0] = 0.0;
#pragma unroll
  for (int e = 0; e < EPT; e++) s_cnt[arr][base + e] = 1;
  __syncthreads();

  // ---- divide & conquer PAV (non-increasing isotonic) ---------------------
  // invariant: block [a,b] has s_cnt[a] == s_cnt[b] == b-a+1
  for (int m = 1; m < NEL; m <<= 1) {
    const int nmerge = NEL / (2 * m);
    for (int t = tA; t < nmerge; t += HALF) {
      const int lo = t * 2 * m, mid = lo + m, hi = lo + 2 * m;
      const int llen = s_cnt[arr][mid - 1];
      int cs = mid - llen;
      const int rlen = s_cnt[arr][mid];
      int ce = mid + rlen - 1;
      const double mL = (s_P[arr][mid] - s_P[arr][cs]) / (double)llen;
      const double mR = (s_P[arr][ce + 1] - s_P[arr][mid]) / (double)rlen;
      if (mL <= mR) {                  // boundary violation -> pool
        double mu = (s_P[arr][ce + 1] - s_P[arr][cs]) / (double)(ce - cs + 1);
        bool changed = true;
        while (changed) {
          changed = false;
          while (cs > lo) {            // absorb left blocks with mean <= mu
            const int l2 = s_cnt[arr][cs - 1];
            const double m2 = (s_P[arr][cs] - s_P[arr][cs - l2]) / (double)l2;
            if (m2 <= mu) {
              cs -= l2;
              mu = (s_P[arr][ce + 1] - s_P[arr][cs]) / (double)(ce - cs + 1);
              changed = true;
            } else break;
          }
          while (ce < hi - 1) {        // absorb right blocks with mean >= mu
            const int l2 = s_cnt[arr][ce + 1];
            const double m2 = (s_P[arr][ce + 1 + l2] - s_P[arr][ce + 1]) / (double)l2;
            if (m2 >= mu) {
              ce += l2;
              mu = (s_P[arr][ce + 1] - s_P[arr][cs]) / (double)(ce - cs + 1);
              changed = true;
            } else break;
          }
        }
        const int len = ce - cs + 1;
        s_cnt[arr][cs] = len;
        s_cnt[arr][ce] = len;
      }
    }
    __syncthreads();
  }

  // ---- walk block list (s_cnt aliased to bstart; reads lead writes) -------
  if (tA == 0) {
    int s = 0, b = 0;
    while (s < NEL) {
      const int cc = s_cnt[arr][s];    // read BEFORE aliased write
      s_cnt[arr][b] = s;
      b++;
      s += cc;
    }
    s_nb[arr] = b;
  }
  __syncthreads();
  const int nb = s_nb[arr];

  // ---- rank at each sorted position: rank = s - blockmean -----------------
  float rv[EPT];
#pragma unroll
  for (int e = 0; e < EPT; e++) {
    const int p = base + e;            // sorted position
    int loB = 0, hiB = nb - 1;
    while (loB < hiB) {
      const int md = (loB + hiB + 1) >> 1;
      if (s_cnt[arr][md] <= p) loB = md; else hiB = md - 1;
    }
    const int st = s_cnt[arr][loB];
    const int en = (loB + 1 < nb) ? s_cnt[arr][loB + 1] : NEL;
    const double v = (s_P[arr][en] - s_P[arr][st]) / (double)(en - st);
    rv[e] = (float)((double)s_val[arr][p] - v);
  }
  __syncthreads();                     // all bstart reads done

  // publish rank_sorted (reuse s_cnt storage as float)
  float* rs = (float*)s_cnt[arr];
#pragma unroll
  for (int e = 0; e < EPT; e++) rs[base + e] = rv[e];
  __syncthreads();

  // gather by original index: element i sits at sorted pos r[e]
#pragma unroll
  for (int e = 0; e < EPT; e++) s_val[arr][base + e] = rs[r[e]];
  __syncthreads();

  // ---- Pearson correlation over 4096 aligned pairs (double raw moments) ---
  double Sp = 0.0, St = 0.0, Spp = 0.0, Stt = 0.0, Spt = 0.0;
#pragma unroll
  for (int e = 0; e < NEL / NT; e++) {
    const int i = tid * (NEL / NT) + e;
    const double p = (double)s_val[0][i];
    const double t = (double)s_val[1][i];
    Sp += p; St += t; Spp += p * p; Stt += t * t; Spt += p * t;
  }
#pragma unroll
  for (int d = 32; d > 0; d >>= 1) {
    Sp  += __shfl_down(Sp,  d, 64);
    St  += __shfl_down(St,  d, 64);
    Spp += __shfl_down(Spp, d, 64);
    Stt += __shfl_down(Stt, d, 64);
    Spt += __shfl_down(Spt, d, 64);
  }
  const int wid = tid >> 6;
  if (lane == 0) {
    s_red[wid][0] = Sp;  s_red[wid][1] = St;  s_red[wid][2] = Spp;
    s_red[wid][3] = Stt; s_red[wid][4] = Spt;
  }
  __syncthreads();
  if (tid == 0) {
    double a0 = 0, a1 = 0, a2 = 0, a3 = 0, a4 = 0;
    for (int w = 0; w < NT / 64; w++) {
      a0 += s_red[w][0]; a1 += s_red[w][1]; a2 += s_red[w][2];
      a3 += s_red[w][3]; a4 += s_red[w][4];
    }
    const double n  = (double)NEL;
    const double mp = a0 / n, mt = a1 / n;
    const double cov = a4 - n * mp * mt;
    const double vp  = a2 - n * mp * mp;
    const double vt  = a3 - n * mt * mt;
    loss_out[0] = (float)(1.0 - cov / sqrt(vp * vt));
  }
}

// ---------------------------------------------------------------------------
extern "C" void kernel_launch(void* const* d_in, const int* in_sizes, int n_in,
                              void* d_out, int out_size, void* d_ws, size_t ws_size,
                              hipStream_t stream) {
  const float* pred   = (const float*)d_in[0];
  const float* target = (const float*)d_in[1];
  int*   counts = (int*)d_ws;              // 2 * NEL ints = 32 KB
  float* out    = (float*)d_out;

  hipMemsetAsync(counts, 0, 2 * NEL * sizeof(int), stream);
  hipLaunchKernelGGL(count_kernel, dim3(NEL / CB, NEL / CB, 2), dim3(CB), 0,
                     stream, pred, target, counts);
  hipLaunchKernelGGL(pav_loss_kernel, dim3(1), dim3(NT), 0, stream,
                     pred, target, counts, out);
}